// Round 8
// baseline (155.881 us; speedup 1.0000x reference)
//
#include <hip/hip_runtime.h>

// GeneralizedRecallLoss — fused single kernel, 6 VALU + 1 trans per eval.
// scores (512, 8192) f32, k_vals (3,) i32, pos_num=16. Output: 1 f32 scalar.
//
// Per pair (t = (neg - pos[j] + 0.1) * 10*log2e):
//   f(d) = ln2*max(t,0) + 0.1*[t>=0] + ln2*log2(1 + 2^min(-t,10t))
// Tricks:
//   Σ max(t,0) = (Σt + Σ|t|)/2 with Σt = suma - 16*p10[j]  (suma j-indep)
//     -> per-eval cost is ONE v_add with free |.| input modifier.
//   Σ log2(1+2^arg) kept as running product, one v_log_f32 per (lane,j):
//     16 factors in (1,2] -> prod <= 2^16, no overflow.
//   [t>=0] via ballot + s_bcnt1 (scalar pipe, wave-uniform SGPR counters).
//   Tail pads use neg=-100 (t ~ -1.4e3): exp2 -> 0, |t| cancels in
//   (Σt+Σ|t|)/2 to ~1e-4, counted as t<0. Exactly 4 pad slots
//   (wave 7, it 3, lanes 60..63).
// Block = row (512 blocks x 512 thr = 8 waves); each wave owns a disjoint
// 256-f4 slice and all 16 j's. No workspace, no second kernel.

#define ROWS 512
#define COLS 8192
#define POSN 16
#define NK 3
#define NEGF4 2044
#define BLOCK 512

typedef float f32x4 __attribute__((ext_vector_type(4)));

__global__ __launch_bounds__(BLOCK, 4)
void recall_fused_kernel(const float* __restrict__ scores,
                         const int* __restrict__ k_vals,
                         float* __restrict__ out)
{
    const int row  = blockIdx.x;
    const int tid  = threadIdx.x;
    const int wave = tid >> 6;
    const int lane = tid & 63;
    const float* rowp = scores + (size_t)row * COLS;

    const float C10 = 14.4269504089f;        // 10*log2(e)
    const float A0  = 1.44269504089f;        // 0.1*C10 (margin pre-folded)
    const float LN2 = 0.69314718055994531f;

    __shared__ float s_part[8][POSN];

    const f32x4* negs = reinterpret_cast<const f32x4*>(rowp + POSN);

    // this wave's disjoint 256-f4 slice; all 4 loads in flight up-front
    f32x4 v[4];
    bool ok[4];
#pragma unroll
    for (int it = 0; it < 4; ++it) {
        const int f = wave * 256 + it * 64 + lane;
        ok[it] = (f < NEGF4);
        v[it] = negs[ok[it] ? f : (NEGF4 - 1)];
    }
#pragma unroll
    for (int it = 0; it < 4; ++it) {
        if (!ok[it]) { v[it].x = -100.0f; v[it].y = -100.0f;
                       v[it].z = -100.0f; v[it].w = -100.0f; }
    }

    // wave-uniform pos values (s_load) + scaled copies
    float p_s[POSN], p10[POSN];
#pragma unroll
    for (int j = 0; j < POSN; ++j) { p_s[j] = rowp[j]; p10[j] = p_s[j] * C10; }

    float prod[POSN], sumabs[POSN];
    int   nge[POSN];                       // wave-uniform (SGPR) counters
    float suma = 0.0f;
#pragma unroll
    for (int j = 0; j < POSN; ++j) { prod[j] = 1.0f; sumabs[j] = 0.0f; nge[j] = 0; }

#pragma unroll
    for (int it = 0; it < 4; ++it) {
        float a10[4];
        a10[0] = __fmaf_rn(v[it].x, C10, A0);
        a10[1] = __fmaf_rn(v[it].y, C10, A0);
        a10[2] = __fmaf_rn(v[it].z, C10, A0);
        a10[3] = __fmaf_rn(v[it].w, C10, A0);
        suma += (a10[0] + a10[1]) + (a10[2] + a10[3]);
#pragma unroll
        for (int e = 0; e < 4; ++e) {
#pragma unroll
            for (int j = 0; j < POSN; ++j) {
                const float t   = a10[e] - p10[j];                 // 1 sub
                const float arg = fminf(-t, 10.0f * t);            // mul+min
                const float u   = __builtin_amdgcn_exp2f(arg);     // 1 trans
                prod[j]   = __fmaf_rn(prod[j], u, prod[j]);        // 1 fma
                sumabs[j] += fabsf(t);                             // add |.|
                nge[j] += (int)__popcll(__ballot(t >= 0.0f));      // cmp+SALU
            }
        }
    }

    // per-lane: ln2*((Σt+Σ|t|)/2 + log2 prod); nge added once on lane 0
#pragma unroll
    for (int j = 0; j < POSN; ++j) {
        float s = (suma - 16.0f * p10[j] + sumabs[j]) * 0.5f
                + __builtin_amdgcn_logf(prod[j]);                  // log2
#pragma unroll
        for (int off = 32; off > 0; off >>= 1)
            s += __shfl_xor(s, off);
        if (lane == 0)
            s_part[wave][j] = __fmaf_rn(s, LN2, 0.1f * (float)nge[j]);
    }
    __syncthreads();

    if (tid < POSN) {
        const int j = tid;
        float negsum = 0.0f;
#pragma unroll
        for (int w = 0; w < 8; ++w) negsum += s_part[w][j];

        const float pj = rowp[j];          // divergent-index load, not p_s[]
        float cnt = -1.0f;                 // remove i==j diagonal
#pragma unroll
        for (int i = 0; i < POSN; ++i)
            cnt += (p_s[i] >= pj) ? 1.0f : 0.0f;

        const float rank = 1.0f + cnt + negsum;

        float rsum = 0.0f;
#pragma unroll
        for (int k = 0; k < NK; ++k) {
            float z = (rank - (float)k_vals[k]) * 10.0f;
            z = fminf(z, 88.0f);
            const float e2 = __builtin_amdgcn_exp2f(-1.44269504089f * fabsf(z));
            rsum += fmaxf(z, 0.0f) + LN2 * __builtin_amdgcn_logf(1.0f + e2);
        }

        rsum += __shfl_xor(rsum, 8);
        rsum += __shfl_xor(rsum, 4);
        rsum += __shfl_xor(rsum, 2);
        rsum += __shfl_xor(rsum, 1);
        if (j == 0)
            atomicAdd(out, rsum * (1.0f / ((float)POSN * NK * ROWS)));
    }
}

extern "C" void kernel_launch(void* const* d_in, const int* in_sizes, int n_in,
                              void* d_out, int out_size, void* d_ws, size_t ws_size,
                              hipStream_t stream) {
    const float* scores = (const float*)d_in[0];
    const int*   k_vals = (const int*)d_in[1];
    float* out = (float*)d_out;

    hipMemsetAsync(out, 0, sizeof(float), stream);
    recall_fused_kernel<<<ROWS, BLOCK, 0, stream>>>(scores, k_vals, out);
}

// Round 10
// 77.702 us; speedup vs baseline: 2.0061x; 2.0061x over previous
//
#include <hip/hip_runtime.h>

// GeneralizedRecallLoss — fused kernel with exact saturation early-exit.
// scores (512, 8192) f32, k_vals (3,) i32, pos_num=16. Output: 1 f32 scalar.
//
// Key identity: for d = neg - pos_j + 0.1 >= 0, the neg term is
//   softplus(d/0.1) + 0.1 >= ln2 + 0.1 = 0.7931.
// So rank >= 1 + 0.7931*cnt_ge with cnt_ge = #{negs >= pos_j - 0.1}.
// If rank >= k_max + 8.8 then z = (rank-k)*10 >= 88 for every k, the clamp
// hits, and recall = logaddexp(0, 88) = 88.0f EXACTLY in f32 (reference
// computes the same 88.0f: log1p(e^-88) ~ 6e-39 vanishes). So cells with
// cnt_ge >= thresh need only the counting pass (1 v_cmp + 2 SALU per pair).
// Cells below threshold (pos_j ~ >2.8 sigma; ~20 in the dataset) run the
// exact pass with data already in registers. Correct for ANY input.
//
// Exact pass per pair (t = (neg - pos_j + 0.1)*10*log2e, one fused fma):
//   f(d) = ln2*((St + S|t|)/2 + log2 prod) + 0.1*#(t>=0),
//   prod *= (1 + 2^min(-t,10t)); St from sumneg (precomputed).
//
// Geometry: block = row, 512 threads; each thread holds 16 negs (4x f4).
// 4 overrun slots (tid>=508, it=3) padded with -1e4: never counted
// (no pos is < -9999), exp-flushed to 0, |t| cancels in (St+S|t|)/2 to ~0.02
// on the (cold) exact path only. Register demand ~45 (spill-safe < 64;
// R5/R8 lesson: demand > 64 => scratch spill catastrophe).

#define ROWS 512
#define COLS 8192
#define POSN 16
#define NK 3
#define BLOCK 512
#define ROWF4 (COLS / 4)

typedef float f32x4 __attribute__((ext_vector_type(4)));

__global__ __launch_bounds__(BLOCK, 4)
void recall_kernel(const float* __restrict__ scores,
                   const int* __restrict__ k_vals,
                   float* __restrict__ out)
{
    const int row  = blockIdx.x;
    const int tid  = threadIdx.x;
    const int wave = tid >> 6;
    const int lane = tid & 63;
    const float* rowp = scores + (size_t)row * COLS;
    const f32x4* rf4  = reinterpret_cast<const f32x4*>(rowp);

    __shared__ int   s_cnt[POSN];
    __shared__ float s_red[POSN][8][2];

    // issue all 4 row loads up-front (16 negs/thread covers the whole row)
    f32x4 v[4];
    bool ok[4];
#pragma unroll
    for (int it = 0; it < 4; ++it) {
        const int f = 4 + tid + BLOCK * it;      // f4 index; negs start at f4=4
        ok[it] = (f < ROWF4);
        v[it]  = rf4[ok[it] ? f : (ROWF4 - 1)];
    }
    if (tid < POSN) s_cnt[tid] = 0;
#pragma unroll
    for (int it = 0; it < 4; ++it)
        if (!ok[it]) { v[it].x = -1.0e4f; v[it].y = -1.0e4f;
                       v[it].z = -1.0e4f; v[it].w = -1.0e4f; }

    float neg[16];
#pragma unroll
    for (int it = 0; it < 4; ++it) {
        neg[it * 4 + 0] = v[it].x; neg[it * 4 + 1] = v[it].y;
        neg[it * 4 + 2] = v[it].z; neg[it * 4 + 3] = v[it].w;
    }

    float p[POSN];
#pragma unroll
    for (int j = 0; j < POSN; ++j) p[j] = rowp[j];   // wave-uniform

    float sumneg = 0.0f;
#pragma unroll
    for (int e = 0; e < 16; ++e) sumneg += neg[e];

    __syncthreads();                                  // s_cnt zeroed

    // ---- cheap pass: count negs >= p[j]-0.1 (1 v_cmp + ballot/bcnt each)
#pragma unroll
    for (int j = 0; j < POSN; ++j) {
        const float pjm = p[j] - 0.1f;
        int c = 0;
#pragma unroll
        for (int e = 0; e < 16; ++e)
            c += (int)__popcll(__ballot(neg[e] >= pjm));
        if (lane == 0) atomicAdd(&s_cnt[j], c);
    }
    __syncthreads();

    int kmax = k_vals[0];
    kmax = max(kmax, k_vals[1]);
    kmax = max(kmax, k_vals[2]);
    // skip-safe iff cnt >= (kmax+7.8)/0.7931 + 2  (+2 = tie/rounding margin)
    const float cthresh = ((float)kmax + 7.8f) * (1.0f / 0.7931f) + 2.0f;

    const float C10 = 14.4269504089f;      // 10*log2(e)
    const float A0  = 1.44269504089f;      // 0.1*C10
    const float LN2 = 0.69314718055994531f;

    // ---- exact pass, flagged j's only (block-uniform branch; data in regs)
#pragma unroll 1
    for (int j = 0; j < POSN; ++j) {
        if ((float)s_cnt[j] < cthresh) {
            const float off = A0 - p[j] * C10;        // t = neg*C10 + off
            float prod = 1.0f, sumabs = 0.0f;
            int icnt = 0;
#pragma unroll
            for (int e = 0; e < 16; ++e) {
                const float t   = __fmaf_rn(neg[e], C10, off);
                const float arg = fminf(-t, 10.0f * t);
                const float u   = __builtin_amdgcn_exp2f(arg);
                prod = __fmaf_rn(prod, u, prod);
                sumabs += fabsf(t);
                icnt += (int)(__float_as_uint(t) >> 31);  // t < 0
            }
            const float st = __fmaf_rn(sumneg, C10, 16.0f * off);  // sum t
            float s  = (st + sumabs) * 0.5f + __builtin_amdgcn_logf(prod);
            float fc = (float)(16 - icnt);                          // t >= 0
#pragma unroll
            for (int o = 32; o > 0; o >>= 1) {
                s  += __shfl_xor(s, o);
                fc += __shfl_xor(fc, o);
            }
            if (lane == 0) { s_red[j][wave][0] = s; s_red[j][wave][1] = fc; }
        }
    }
    __syncthreads();

    // ---- finalize: one lane per j
    if (tid < POSN) {
        const int j = tid;
        float rsum;
        if ((float)s_cnt[j] < cthresh) {
            float ssum = 0.0f, fcsum = 0.0f;
#pragma unroll
            for (int w = 0; w < 8; ++w) {
                ssum  += s_red[j][w][0];
                fcsum += s_red[j][w][1];
            }
            const float negsum = __fmaf_rn(ssum, LN2, 0.1f * fcsum);

            const float pj = p[j];
            float pcnt = -1.0f;                       // remove i==j diagonal
#pragma unroll
            for (int i = 0; i < POSN; ++i)
                pcnt += (p[i] >= pj) ? 1.0f : 0.0f;

            const float rank = 1.0f + pcnt + negsum;
            rsum = 0.0f;
#pragma unroll
            for (int k = 0; k < NK; ++k) {
                float z = (rank - (float)k_vals[k]) * 10.0f;
                z = fminf(z, 88.0f);
                const float e2 =
                    __builtin_amdgcn_exp2f(-1.44269504089f * fabsf(z));
                rsum += fmaxf(z, 0.0f)
                      + LN2 * __builtin_amdgcn_logf(1.0f + e2);
            }
        } else {
            rsum = 264.0f;          // 3 saturated cells x 88.0, exact
        }

        rsum += __shfl_xor(rsum, 8);
        rsum += __shfl_xor(rsum, 4);
        rsum += __shfl_xor(rsum, 2);
        rsum += __shfl_xor(rsum, 1);
        if (j == 0)
            atomicAdd(out, rsum * (1.0f / ((float)POSN * NK * ROWS)));
    }
}

extern "C" void kernel_launch(void* const* d_in, const int* in_sizes, int n_in,
                              void* d_out, int out_size, void* d_ws, size_t ws_size,
                              hipStream_t stream) {
    const float* scores = (const float*)d_in[0];
    const int*   k_vals = (const int*)d_in[1];
    float* out = (float*)d_out;

    hipMemsetAsync(out, 0, sizeof(float), stream);
    recall_kernel<<<ROWS, BLOCK, 0, stream>>>(scores, k_vals, out);
}